// Round 11
// baseline (125.461 us; speedup 1.0000x reference)
//
#include <hip/hip_runtime.h>
#include <math.h>
#include <stdint.h>

// Problem constants (match reference)
constexpr int kVerts = 5000;
constexpr int kFaces = 10000;
constexpr int kPts   = 16384;   // BATCH * N_PTS = 2 * 8192
constexpr int kOuter = 4;
constexpr int kInner = 50;

#define SCALE 10.0f

// KNN structure: 8 points per lane, 16 waves per block, 8 face segments.
// Grid = 32 point-groups x 8 segments = 256 blocks (1 block/CU, 16 waves,
// 4 waves/SIMD). 512 pts/wave -> 1250 b128 broadcast reads/CU.
#define KNN_WAVES 16
#define KNN_SEG   8
constexpr int kSeg         = kFaces / KNN_SEG;       // 1250
constexpr int kPairsE      = kSeg / 2;               // 625
constexpr int kPtsPerLane  = 8;
constexpr int kPtsPerBlock = 64 * kPtsPerLane;       // 512
constexpr int kPtGroups    = kPts / kPtsPerBlock;    // 32

typedef float v2f __attribute__((ext_vector_type(2)));

// ---------------------------------------------------------------------------
// Adam bias-correction table (same constexpr values as all prior rounds).
// ---------------------------------------------------------------------------
struct BiasTabP { float rb[kInner + 2][2]; };
constexpr BiasTabP make_tabp() {
    BiasTabP t{};
    float b1 = 1.0f, b2 = 1.0f;
    for (int i = 0; i < kInner; ++i) {
        b1 *= 0.9f; b2 *= 0.999f;
        t.rb[i][0] = 1.0f / (1.0f - b1);
        t.rb[i][1] = 1.0f / (1.0f - b2);
    }
    t.rb[kInner][0]     = t.rb[kInner - 1][0];
    t.rb[kInner][1]     = t.rb[kInner - 1][1];
    t.rb[kInner + 1][0] = t.rb[kInner - 1][0];
    t.rb[kInner + 1][1] = t.rb[kInner - 1][1];
    return t;
}
constexpr BiasTabP kTabP = make_tabp();

// ---------------------------------------------------------------------------
// Kernel 0: triangle centers, SoA output — REINSTATED (round-11).
// The r8 in-block fusion (64x redundant dependent mesh_F->mesh_V gathers)
// was never A/B-isolated and is the prime suspect for knn's ~2.5x-over-
// floor duty cycle. This kernel measured ~2us in rounds 0-7.
// Bit-identical *_rn formulas as every prior round.
// ---------------------------------------------------------------------------
__global__ __launch_bounds__(256)
void centers_kernel(const float* __restrict__ mesh_V,
                    const int*   __restrict__ mesh_F,
                    float*       __restrict__ soa)   // [4][kFaces]
{
    const int f = blockIdx.x * 256 + threadIdx.x;
    if (f >= kFaces) return;
    const int i0 = mesh_F[f * 3 + 0];
    const int i1 = mesh_F[f * 3 + 1];
    const int i2 = mesh_F[f * 3 + 2];
    const float cx = __fdiv_rn(__fadd_rn(__fadd_rn(mesh_V[i0*3+0], mesh_V[i1*3+0]), mesh_V[i2*3+0]), 3.0f);
    const float cy = __fdiv_rn(__fadd_rn(__fadd_rn(mesh_V[i0*3+1], mesh_V[i1*3+1]), mesh_V[i2*3+1]), 3.0f);
    const float cz = __fdiv_rn(__fadd_rn(__fadd_rn(mesh_V[i0*3+2], mesh_V[i1*3+2]), mesh_V[i2*3+2]), 3.0f);
    const float cc = __fadd_rn(__fadd_rn(__fmul_rn(cx, cx), __fmul_rn(cy, cy)),
                               __fmul_rn(cz, cz));
    soa[0 * kFaces + f] = cx;
    soa[1 * kFaces + f] = cy;
    soa[2 * kFaces + f] = cz;
    soa[3 * kFaces + f] = cc;
}

// ---------------------------------------------------------------------------
// Kernel 1: KNN (K=1).
// Round-11 changes (unbundling r8's never-isolated staging fusion):
//  (a) stage LDS from ws_soa with pure coalesced v2f loads + b128 writes
//      (no dependent gather chains inside the block);
//  (b) explicit software pipeline in the scan: load pair i+1 into registers
//      BEFORE evaluating pair i, hiding the ~120cyc ds_read latency under
//      the ~192cyc eval block (the old loop re-loaded at the loop head,
//      exposing the latency every 2 pairs at only 4 waves/SIMD of cover).
// Eval core unchanged from r10 (FMA chain, 6 insts/eval, branch-free
// selects) -> distance bits unchanged -> fidx and absmax must be identical.
// Tie semantics: even->acc0/odd->acc1 ascending; all merges lexicographic
// (s, f) => partition-independent first-occurrence argmin.
// LDS: 10000 + 10000 + 32768 + 32768 = 85536 B -> 1 block/CU.
// ---------------------------------------------------------------------------
__global__ __launch_bounds__(1024, 4)
void knn_kernel(const float* __restrict__ verts,
                const float* __restrict__ soa,      // [4][kFaces]
                float*       __restrict__ ws_d2,    // [KNN_SEG][kPts]
                int*         __restrict__ ws_f)     // [KNN_SEG][kPts]
{
    __shared__ float4 s_A[kPairsE];                        // {cx_e,cx_o,cy_e,cy_o}
    __shared__ float4 s_B[kPairsE];                        // {cz_e,cz_o,cc_e,cc_o}
    __shared__ float  s_best [KNN_WAVES][kPtsPerBlock];    // 32768 B
    __shared__ int    s_bestf[KNN_WAVES][kPtsPerBlock];    // 32768 B

    const int tid  = threadIdx.x;
    const int lane = tid & 63;
    const int wv   = __builtin_amdgcn_readfirstlane(tid >> 6);   // 0..15
    const int pg   = blockIdx.x >> 3;   // point group 0..31
    const int fq   = blockIdx.x & 7;    // face segment 0..7
    const int qbeg = fq * kSeg;

    // ---- stage segment as pair-interleaved SoA (coalesced v2f loads,
    //      consecutive-float4 b128 writes) ----
    for (int p = tid; p < kPairsE; p += 1024) {
        const v2f cx2 = *reinterpret_cast<const v2f*>(soa + 0 * kFaces + qbeg + 2 * p);
        const v2f cy2 = *reinterpret_cast<const v2f*>(soa + 1 * kFaces + qbeg + 2 * p);
        const v2f cz2 = *reinterpret_cast<const v2f*>(soa + 2 * kFaces + qbeg + 2 * p);
        const v2f cc2 = *reinterpret_cast<const v2f*>(soa + 3 * kFaces + qbeg + 2 * p);
        s_A[p] = make_float4(cx2.x, cx2.y, cy2.x, cy2.y);
        s_B[p] = make_float4(cz2.x, cz2.y, cc2.x, cc2.y);
    }

    // ---- per-lane 8 points: pre-negated doubled coords (exact), scalar,
    //      laundered once (loop-invariant, no remat) ----
    float ndx[kPtsPerLane], ndy[kPtsPerLane], ndz[kPtsPerLane];
#pragma unroll
    for (int k = 0; k < kPtsPerLane; ++k) {
        const int p = pg * kPtsPerBlock + k * 64 + lane;
        const float qx = verts[p * 3 + 0];
        const float qy = verts[p * 3 + 1];
        const float qz = verts[p * 3 + 2];
        ndx[k] = -__fmul_rn(2.0f, qx);  asm("" : "+v"(ndx[k]));
        ndy[k] = -__fmul_rn(2.0f, qy);  asm("" : "+v"(ndy[k]));
        ndz[k] = -__fmul_rn(2.0f, qz);  asm("" : "+v"(ndz[k]));
    }

    float bd0[kPtsPerLane], bd1[kPtsPerLane];
    int   bf0[kPtsPerLane], bf1[kPtsPerLane];
#pragma unroll
    for (int k = 0; k < kPtsPerLane; ++k) {
        bd0[k] = INFINITY;   bd1[k] = INFINITY;
        bf0[k] = 0x7fffffff; bf1[k] = 0x7fffffff;
    }

    __syncthreads();

    // this wave's contiguous pair slice (>= 39 pairs, never empty)
    const int pbeg = (wv * kPairsE) / KNN_WAVES;
    const int pend = ((wv + 1) * kPairsE) / KNN_WAVES;

    // 16 evals of one face pair against this lane's 8 points
#define KNN_PAIR_EVALS(AB, ZB, GF)                                            \
    {                                                                         \
        const int gf_  = (GF);                                                \
        const int gf1_ = gf_ + 1;                                             \
        _Pragma("unroll")                                                     \
        for (int k = 0; k < kPtsPerLane; ++k) {                               \
            const float s0 = __builtin_fmaf(ndx[k], (AB).x,                   \
                             __builtin_fmaf(ndy[k], (AB).z,                   \
                             __builtin_fmaf(ndz[k], (ZB).x, (ZB).z)));        \
            const float s1 = __builtin_fmaf(ndx[k], (AB).y,                   \
                             __builtin_fmaf(ndy[k], (AB).w,                   \
                             __builtin_fmaf(ndz[k], (ZB).y, (ZB).w)));        \
            bf0[k] = (s0 < bd0[k]) ? gf_  : bf0[k];                           \
            bd0[k] = __builtin_fminf(s0, bd0[k]);                             \
            bf1[k] = (s1 < bd1[k]) ? gf1_ : bf1[k];                           \
            bd1[k] = __builtin_fminf(s1, bd1[k]);                             \
        }                                                                     \
    }

    // software-pipelined scan: fetch pair i+1 before evaluating pair i
    int fp = pbeg;
    float4 a = s_A[fp];
    float4 b = s_B[fp];
#pragma unroll 1
    for (; fp < pend - 1; ++fp) {
        const float4 an = s_A[fp + 1];
        const float4 bn = s_B[fp + 1];
        KNN_PAIR_EVALS(a, b, qbeg + 2 * fp);
        a = an; b = bn;
    }
    KNN_PAIR_EVALS(a, b, qbeg + 2 * fp);
#undef KNN_PAIR_EVALS

    // per-point lexicographic merge of the 2 accumulators (smaller f on ties)
#pragma unroll
    for (int k = 0; k < kPtsPerLane; ++k) {
        if (bd1[k] < bd0[k] || (bd1[k] == bd0[k] && bf1[k] < bf0[k])) {
            bd0[k] = bd1[k]; bf0[k] = bf1[k];
        }
        s_best [wv][k * 64 + lane] = bd0[k];
        s_bestf[wv][k * 64 + lane] = bf0[k];
    }
    __syncthreads();

    // cross-wave merge: fully lexicographic -> partition-independent
    if (tid < kPtsPerBlock) {
        float best  = s_best [0][tid];
        int   bestf = s_bestf[0][tid];
#pragma unroll
        for (int w = 1; w < KNN_WAVES; ++w) {
            const float ob = s_best [w][tid];
            const int   of = s_bestf[w][tid];
            if (ob < best || (ob == best && of < bestf)) { best = ob; bestf = of; }
        }
        const int p = pg * kPtsPerBlock + tid;
        ws_d2[fq * kPts + p] = best;
        ws_f [fq * kPts + p] = bestf;
    }
}

// ---------------------------------------------------------------------------
// quad_perm DPP broadcast: all lanes of each 4-lane quad read lane K.
// ---------------------------------------------------------------------------
template<int K>
__device__ __forceinline__ float qbcast(float v) {
    return __int_as_float(__builtin_amdgcn_update_dpp(
        0, __float_as_int(v), K * 0x55 /*quad_perm[K,K,K,K]*/, 0xF, 0xF, true));
}

// ---------------------------------------------------------------------------
// Kernel 2: solve — FROZEN (round-4 structure: 4 lanes/point, one Adam
// channel per lane, DPP quad broadcasts).
// ---------------------------------------------------------------------------
__global__ __launch_bounds__(256)
void solve_kernel(const float* __restrict__ verts,
                  const float* __restrict__ mesh_V,
                  const float* __restrict__ mesh_N,
                  const int*   __restrict__ mesh_F,
                  const float* __restrict__ ws_d2,
                  const int*   __restrict__ ws_f,
                  float*       __restrict__ out)
{
    const int t  = blockIdx.x * 256 + threadIdx.x;
    const int p  = t >> 2;          // point index
    const int ch = t & 3;           // 0=u, 1=v, 2=d, 3=d-duplicate
    const bool isV = (ch == 1);
    const bool isD = (ch >= 2);

    // merge segments: ascending order + strict < == first-occurrence argmin
    float bdm = ws_d2[p];
    int   f   = ws_f[p];
#pragma unroll
    for (int q = 1; q < KNN_SEG; ++q) {
        const float d  = ws_d2[q * kPts + p];
        const int   ff = ws_f [q * kPts + p];
        if (d < bdm) { bdm = d; f = ff; }
    }
    if (ch == 0) out[p] = (float)f;   // fidx as float (exact for idx < 2^24)

    const float qx = verts[p * 3 + 0];
    const float qy = verts[p * 3 + 1];
    const float qz = verts[p * 3 + 2];

    const int i0 = mesh_F[f * 3 + 0];
    const int i1 = mesh_F[f * 3 + 1];
    const int i2 = mesh_F[f * 3 + 2];

    const float V0x = mesh_V[i0*3+0], V0y = mesh_V[i0*3+1], V0z = mesh_V[i0*3+2];
    const float V1x = mesh_V[i1*3+0], V1y = mesh_V[i1*3+1], V1z = mesh_V[i1*3+2];
    const float V2x = mesh_V[i2*3+0], V2y = mesh_V[i2*3+1], V2z = mesh_V[i2*3+2];
    const float N0x = mesh_N[i0*3+0], N0y = mesh_N[i0*3+1], N0z = mesh_N[i0*3+2];
    const float N1x = mesh_N[i1*3+0], N1y = mesh_N[i1*3+1], N1z = mesh_N[i1*3+2];
    const float N2x = mesh_N[i2*3+0], N2y = mesh_N[i2*3+1], N2z = mesh_N[i2*3+2];

    // edge vectors (same formulas as before)
    const float E0x = V0x - V2x, E0y = V0y - V2y, E0z = V0z - V2z;
    const float E1x = V1x - V2x, E1y = V1y - V2y, E1z = V1z - V2z;
    const float F0x = N0x - N2x, F0y = N0y - N2y, F0z = N0z - N2z;
    const float F1x = N1x - N2x, F1y = N1y - N2y, F1z = N1z - N2z;

    // per-lane operand selects (loop-invariant parts)
    const float Aux = isV ? E1x : E0x;   // A when !isD (the isD case is nh, per-iter)
    const float Auy = isV ? E1y : E0y;
    const float Auz = isV ? E1z : E0z;
    const float Bx  = isD ? 0.0f : (isV ? F1x : F0x);
    const float By  = isD ? 0.0f : (isV ? F1y : F0y);
    const float Bz  = isD ? 0.0f : (isV ? F1z : F0z);

    const float tx = qx * SCALE, ty = qy * SCALE, tz = qz * SCALE;
    const float GS = 2.0f / (3.0f * 16384.0f);
    const float B1c = 0.9f,  ONE_M_B1 = 1.0f - 0.9f;
    const float B2c = 0.999f, ONE_M_B2 = 1.0f - 0.999f;

    float vwu = 1.0f / 3.0f, vwv = 1.0f / 3.0f;

#define SOLVE_STEP(RB1, RB2)                                                   \
    {                                                                          \
        const float du = qbcast<0>(dlt);                                       \
        const float dv = qbcast<1>(dlt);                                       \
        const float dd = qbcast<2>(dlt);                                       \
        const float bu = vwu + du;                                             \
        const float bv = vwv + dv;                                             \
        const float bw = (1.0f - bu) - bv;                                     \
        const float cVx = ((bu * V0x + bv * V1x) + bw * V2x) * SCALE;          \
        const float cVy = ((bu * V0y + bv * V1y) + bw * V2y) * SCALE;          \
        const float cVz = ((bu * V0z + bv * V1z) + bw * V2z) * SCALE;          \
        const float nrx = (bu * N0x + bv * N1x) + bw * N2x;                    \
        const float nry = (bu * N0y + bv * N1y) + bw * N2y;                    \
        const float nrz = (bu * N0z + bv * N1z) + bw * N2z;                    \
        const float nn  = (nrx * nrx + nry * nry) + nrz * nrz;                 \
        const float inv = __builtin_amdgcn_rsqf(nn);                           \
        const float nhx = nrx * inv, nhy = nry * inv, nhz = nrz * inv;         \
        const float cNx = nhx * SCALE, cNy = nhy * SCALE, cNz = nhz * SCALE;   \
        const float rx = (cVx + cNx * dd) - tx;                                \
        const float ry = (cVy + cNy * dd) - ty;                                \
        const float rz = (cVz + cNz * dd) - tz;                                \
        const float Ax = isD ? nhx : Aux;                                      \
        const float Ay = isD ? nhy : Auy;                                      \
        const float Az = isD ? nhz : Auz;                                      \
        const float dotA = (rx * Ax + ry * Ay) + rz * Az;                      \
        const float dotB = (rx * Bx + ry * By) + rz * Bz;                      \
        const float nhB  = (nhx * Bx + nhy * By) + nhz * Bz;                   \
        const float nr_r = qbcast<2>(dotA);                                    \
        const float g = GS * (SCALE * dotA + (dd * SCALE) * ((dotB - nr_r * nhB) * inv)); \
        mA = B1c * mA + ONE_M_B1 * g;                                          \
        vA = B2c * vA + ONE_M_B2 * (g * g);                                    \
        const float s = __builtin_amdgcn_rsqf(vA * (RB2) + 1e-16f);            \
        dlt -= 0.01f * (mA * (RB1)) * s;                                       \
    }

    for (int outer = 0; outer < kOuter; ++outer) {
        const float bw0 = (1.0f - vwu) - vwv;
        const float px = ((vwu * V0x + vwv * V1x) + bw0 * V2x);
        const float py = ((vwu * V0y + vwv * V1y) + bw0 * V2y);
        const float pz = ((vwu * V0z + vwv * V1z) + bw0 * V2z);
        const float dx = px - qx, dy = py - qy, dz = pz - qz;
        const float d0 = __builtin_amdgcn_sqrtf((dx * dx + dy * dy) + dz * dz);

        float dlt = isD ? d0 : 0.0f;   // this lane's channel delta
        float mA  = 0.0f, vA = 0.0f;

        float rbA1 = kTabP.rb[0][0], rbA2 = kTabP.rb[0][1];
        float rbB1 = kTabP.rb[1][0], rbB2 = kTabP.rb[1][1];
#pragma unroll 1
        for (int it2 = 0; it2 < kInner / 2; ++it2) {
            const float n1a = kTabP.rb[2 * it2 + 2][0];
            const float n2a = kTabP.rb[2 * it2 + 2][1];
            const float n1b = kTabP.rb[2 * it2 + 3][0];
            const float n2b = kTabP.rb[2 * it2 + 3][1];
            SOLVE_STEP(rbA1, rbA2);
            SOLVE_STEP(rbB1, rbB2);
            rbA1 = n1a; rbA2 = n2a; rbB1 = n1b; rbB2 = n2b;
        }
        vwu += qbcast<0>(dlt);
        vwv += qbcast<1>(dlt);
    }
#undef SOLVE_STEP

    if (ch == 0) {
        out[kPts + 2 * p + 0] = vwu;
        out[kPts + 2 * p + 1] = vwv;
        out[3 * kPts + p]     = 0.0f;   // outlier_mask = False
    }
}

extern "C" void kernel_launch(void* const* d_in, const int* in_sizes, int n_in,
                              void* d_out, int out_size, void* d_ws, size_t ws_size,
                              hipStream_t stream) {
    const float* verts  = (const float*)d_in[0];
    const float* mesh_V = (const float*)d_in[1];
    const float* mesh_N = (const float*)d_in[2];
    const int*   mesh_F = (const int*)d_in[3];
    float* out = (float*)d_out;

    // workspace layout: SoA centers [4][kFaces] | d2 cand [8][kPts] | f cand
    float* ws_soa = (float*)d_ws;                                           // 160000 B
    float* ws_d2  = (float*)((char*)d_ws + 4 * kFaces * sizeof(float));     // KNN_SEG*kPts floats
    int*   ws_f   = (int*)((char*)ws_d2 + KNN_SEG * kPts * sizeof(float));  // KNN_SEG*kPts ints

    hipLaunchKernelGGL(centers_kernel, dim3((kFaces + 255) / 256), dim3(256), 0, stream,
                       mesh_V, mesh_F, ws_soa);
    hipLaunchKernelGGL(knn_kernel,     dim3(kPtGroups * KNN_SEG), dim3(1024), 0, stream,
                       verts, ws_soa, ws_d2, ws_f);
    hipLaunchKernelGGL(solve_kernel,   dim3(kPts * 4 / 256), dim3(256), 0, stream,
                       verts, mesh_V, mesh_N, mesh_F, ws_d2, ws_f, out);
}

// Round 12
// 119.695 us; speedup vs baseline: 1.0482x; 1.0482x over previous
//
#include <hip/hip_runtime.h>
#include <math.h>
#include <stdint.h>

// Problem constants (match reference)
constexpr int kVerts = 5000;
constexpr int kFaces = 10000;
constexpr int kPts   = 16384;   // BATCH * N_PTS = 2 * 8192
constexpr int kOuter = 4;
constexpr int kInner = 50;

#define SCALE 10.0f

// KNN structure (round-12): 4 points per lane, 16 waves per block, 8 face
// segments. Grid = 64 point-groups x 8 segments = 512 blocks. LDS 52.8KB
// -> 2 blocks/CU -> 32 waves/CU (100% cap; r10's 85.5KB allowed only 16).
// LDS broadcast reads double to 2500 b128/CU (~12.5us) -- still under the
// measured ~27us VALU issue load, so not limiting.
#define KNN_WAVES 16
#define KNN_SEG   8
constexpr int kSeg         = kFaces / KNN_SEG;       // 1250
constexpr int kPairsE      = kSeg / 2;               // 625
constexpr int kPtsPerLane  = 4;
constexpr int kPtsPerBlock = 64 * kPtsPerLane;       // 256
constexpr int kPtGroups    = kPts / kPtsPerBlock;    // 64

// ---------------------------------------------------------------------------
// Adam bias-correction table (same constexpr values as all prior rounds).
// ---------------------------------------------------------------------------
struct BiasTabP { float rb[kInner + 2][2]; };
constexpr BiasTabP make_tabp() {
    BiasTabP t{};
    float b1 = 1.0f, b2 = 1.0f;
    for (int i = 0; i < kInner; ++i) {
        b1 *= 0.9f; b2 *= 0.999f;
        t.rb[i][0] = 1.0f / (1.0f - b1);
        t.rb[i][1] = 1.0f / (1.0f - b2);
    }
    t.rb[kInner][0]     = t.rb[kInner - 1][0];
    t.rb[kInner][1]     = t.rb[kInner - 1][1];
    t.rb[kInner + 1][0] = t.rb[kInner - 1][0];
    t.rb[kInner + 1][1] = t.rb[kInner - 1][1];
    return t;
}
constexpr BiasTabP kTabP = make_tabp();

// ---------------------------------------------------------------------------
// Kernel 1: KNN (K=1), centers fused (r10 structure — best measured config).
// r11 A/B results: separate-centers staging and software pipelining both
// NEUTRAL-to-negative -> knn is issue-bound (VALUBusy 68%), occupancy-capped
// (36%, 1 block/CU from 85.5KB LDS). This round: 4 pts/lane shrinks merge
// scratch to [16][256] (32KB), LDS 52.8KB -> 2 blocks/CU, grid 512 -> 32
// waves/CU. Eval core unchanged from r10 (FMA chain, 6 insts/eval,
// branch-free selects) -> distance bits identical -> fidx/absmax identical.
// Tie semantics: even->acc0/odd->acc1 ascending; all merges lexicographic
// (s, f) => partition-independent first-occurrence argmin.
// LDS: 10000 (s_A) + 10000 (s_B) + 16384 + 16384 = 52768 B.
// ---------------------------------------------------------------------------
__global__ __launch_bounds__(1024, 8)
void knn_kernel(const float* __restrict__ verts,
                const float* __restrict__ mesh_V,
                const int*   __restrict__ mesh_F,
                float*       __restrict__ ws_d2,    // [KNN_SEG][kPts]
                int*         __restrict__ ws_f)     // [KNN_SEG][kPts]
{
    __shared__ float4 s_A[kPairsE];                        // {cx_e,cx_o,cy_e,cy_o}
    __shared__ float4 s_B[kPairsE];                        // {cz_e,cz_o,cc_e,cc_o}
    __shared__ float  s_best [KNN_WAVES][kPtsPerBlock];    // 16384 B
    __shared__ int    s_bestf[KNN_WAVES][kPtsPerBlock];    // 16384 B

    const int tid  = threadIdx.x;
    const int lane = tid & 63;
    const int wv   = __builtin_amdgcn_readfirstlane(tid >> 6);   // 0..15
    const int pg   = blockIdx.x >> 3;   // point group 0..63
    const int fq   = blockIdx.x & 7;    // face segment 0..7
    const int qbeg = fq * kSeg;

    // ---- fused centers: one face-pair per thread, b128 writes ----
    // (bit-identical *_rn formulas as every prior round)
    for (int j = tid; j < kPairsE; j += 1024) {
        const int f0 = qbeg + 2 * j;
        const int f1 = f0 + 1;
        const int a0 = mesh_F[f0 * 3 + 0], a1 = mesh_F[f0 * 3 + 1], a2 = mesh_F[f0 * 3 + 2];
        const int b0 = mesh_F[f1 * 3 + 0], b1 = mesh_F[f1 * 3 + 1], b2 = mesh_F[f1 * 3 + 2];
        const float cx0 = __fdiv_rn(__fadd_rn(__fadd_rn(mesh_V[a0*3+0], mesh_V[a1*3+0]), mesh_V[a2*3+0]), 3.0f);
        const float cy0 = __fdiv_rn(__fadd_rn(__fadd_rn(mesh_V[a0*3+1], mesh_V[a1*3+1]), mesh_V[a2*3+1]), 3.0f);
        const float cz0 = __fdiv_rn(__fadd_rn(__fadd_rn(mesh_V[a0*3+2], mesh_V[a1*3+2]), mesh_V[a2*3+2]), 3.0f);
        const float cc0 = __fadd_rn(__fadd_rn(__fmul_rn(cx0, cx0), __fmul_rn(cy0, cy0)),
                                    __fmul_rn(cz0, cz0));
        const float cx1 = __fdiv_rn(__fadd_rn(__fadd_rn(mesh_V[b0*3+0], mesh_V[b1*3+0]), mesh_V[b2*3+0]), 3.0f);
        const float cy1 = __fdiv_rn(__fadd_rn(__fadd_rn(mesh_V[b0*3+1], mesh_V[b1*3+1]), mesh_V[b2*3+1]), 3.0f);
        const float cz1 = __fdiv_rn(__fadd_rn(__fadd_rn(mesh_V[b0*3+2], mesh_V[b1*3+2]), mesh_V[b2*3+2]), 3.0f);
        const float cc1 = __fadd_rn(__fadd_rn(__fmul_rn(cx1, cx1), __fmul_rn(cy1, cy1)),
                                    __fmul_rn(cz1, cz1));
        s_A[j] = make_float4(cx0, cx1, cy0, cy1);
        s_B[j] = make_float4(cz0, cz1, cc0, cc1);
    }

    // ---- per-lane 4 points: pre-negated doubled coords (exact), scalar,
    //      laundered once (loop-invariant, no remat) ----
    float ndx[kPtsPerLane], ndy[kPtsPerLane], ndz[kPtsPerLane];
#pragma unroll
    for (int k = 0; k < kPtsPerLane; ++k) {
        const int p = pg * kPtsPerBlock + k * 64 + lane;
        const float qx = verts[p * 3 + 0];
        const float qy = verts[p * 3 + 1];
        const float qz = verts[p * 3 + 2];
        ndx[k] = -__fmul_rn(2.0f, qx);  asm("" : "+v"(ndx[k]));
        ndy[k] = -__fmul_rn(2.0f, qy);  asm("" : "+v"(ndy[k]));
        ndz[k] = -__fmul_rn(2.0f, qz);  asm("" : "+v"(ndz[k]));
    }

    float bd0[kPtsPerLane], bd1[kPtsPerLane];
    int   bf0[kPtsPerLane], bf1[kPtsPerLane];
#pragma unroll
    for (int k = 0; k < kPtsPerLane; ++k) {
        bd0[k] = INFINITY;   bd1[k] = INFINITY;
        bf0[k] = 0x7fffffff; bf1[k] = 0x7fffffff;
    }

    __syncthreads();

    // this wave's contiguous pair slice (~39 pairs)
    const int pbeg = (wv * kPairsE) / KNN_WAVES;
    const int pend = ((wv + 1) * kPairsE) / KNN_WAVES;

#pragma unroll 2
    for (int fp = pbeg; fp < pend; ++fp) {
        // 2 x ds_read_b128 at wave-uniform address (broadcast, in-order)
        const float4 ab = s_A[fp];   // {cx_e, cx_o, cy_e, cy_o}
        const float4 zb = s_B[fp];   // {cz_e, cz_o, cc_e, cc_o}
        const int gf  = qbeg + 2 * fp;
        const int gf1 = gf + 1;
#pragma unroll
        for (int k = 0; k < kPtsPerLane; ++k) {
            // s = cc + (-2q).c as a pure FMA chain: 3 v_fma_f32 per eval
            const float s0 = __builtin_fmaf(ndx[k], ab.x,
                             __builtin_fmaf(ndy[k], ab.z,
                             __builtin_fmaf(ndz[k], zb.x, zb.z)));
            const float s1 = __builtin_fmaf(ndx[k], ab.y,
                             __builtin_fmaf(ndy[k], ab.w,
                             __builtin_fmaf(ndz[k], zb.y, zb.w)));
            // branch-free: v_cmp + v_cndmask (index) + v_min_f32 (dist);
            // strict < keeps the OLD (smaller) face on exact ties.
            bf0[k] = (s0 < bd0[k]) ? gf  : bf0[k];
            bd0[k] = __builtin_fminf(s0, bd0[k]);
            bf1[k] = (s1 < bd1[k]) ? gf1 : bf1[k];
            bd1[k] = __builtin_fminf(s1, bd1[k]);
        }
    }

    // per-point lexicographic merge of the 2 accumulators (smaller f on ties)
#pragma unroll
    for (int k = 0; k < kPtsPerLane; ++k) {
        if (bd1[k] < bd0[k] || (bd1[k] == bd0[k] && bf1[k] < bf0[k])) {
            bd0[k] = bd1[k]; bf0[k] = bf1[k];
        }
        s_best [wv][k * 64 + lane] = bd0[k];
        s_bestf[wv][k * 64 + lane] = bf0[k];
    }
    __syncthreads();

    // cross-wave merge: fully lexicographic -> partition-independent
    if (tid < kPtsPerBlock) {
        float best  = s_best [0][tid];
        int   bestf = s_bestf[0][tid];
#pragma unroll
        for (int w = 1; w < KNN_WAVES; ++w) {
            const float ob = s_best [w][tid];
            const int   of = s_bestf[w][tid];
            if (ob < best || (ob == best && of < bestf)) { best = ob; bestf = of; }
        }
        const int p = pg * kPtsPerBlock + tid;
        ws_d2[fq * kPts + p] = best;
        ws_f [fq * kPts + p] = bestf;
    }
}

// ---------------------------------------------------------------------------
// quad_perm DPP broadcast: all lanes of each 4-lane quad read lane K.
// ---------------------------------------------------------------------------
template<int K>
__device__ __forceinline__ float qbcast(float v) {
    return __int_as_float(__builtin_amdgcn_update_dpp(
        0, __float_as_int(v), K * 0x55 /*quad_perm[K,K,K,K]*/, 0xF, 0xF, true));
}

// ---------------------------------------------------------------------------
// Kernel 2: solve — FROZEN (round-4 structure: 4 lanes/point, one Adam
// channel per lane, DPP quad broadcasts).
// ---------------------------------------------------------------------------
__global__ __launch_bounds__(256)
void solve_kernel(const float* __restrict__ verts,
                  const float* __restrict__ mesh_V,
                  const float* __restrict__ mesh_N,
                  const int*   __restrict__ mesh_F,
                  const float* __restrict__ ws_d2,
                  const int*   __restrict__ ws_f,
                  float*       __restrict__ out)
{
    const int t  = blockIdx.x * 256 + threadIdx.x;
    const int p  = t >> 2;          // point index
    const int ch = t & 3;           // 0=u, 1=v, 2=d, 3=d-duplicate
    const bool isV = (ch == 1);
    const bool isD = (ch >= 2);

    // merge segments: ascending order + strict < == first-occurrence argmin
    float bdm = ws_d2[p];
    int   f   = ws_f[p];
#pragma unroll
    for (int q = 1; q < KNN_SEG; ++q) {
        const float d  = ws_d2[q * kPts + p];
        const int   ff = ws_f [q * kPts + p];
        if (d < bdm) { bdm = d; f = ff; }
    }
    if (ch == 0) out[p] = (float)f;   // fidx as float (exact for idx < 2^24)

    const float qx = verts[p * 3 + 0];
    const float qy = verts[p * 3 + 1];
    const float qz = verts[p * 3 + 2];

    const int i0 = mesh_F[f * 3 + 0];
    const int i1 = mesh_F[f * 3 + 1];
    const int i2 = mesh_F[f * 3 + 2];

    const float V0x = mesh_V[i0*3+0], V0y = mesh_V[i0*3+1], V0z = mesh_V[i0*3+2];
    const float V1x = mesh_V[i1*3+0], V1y = mesh_V[i1*3+1], V1z = mesh_V[i1*3+2];
    const float V2x = mesh_V[i2*3+0], V2y = mesh_V[i2*3+1], V2z = mesh_V[i2*3+2];
    const float N0x = mesh_N[i0*3+0], N0y = mesh_N[i0*3+1], N0z = mesh_N[i0*3+2];
    const float N1x = mesh_N[i1*3+0], N1y = mesh_N[i1*3+1], N1z = mesh_N[i1*3+2];
    const float N2x = mesh_N[i2*3+0], N2y = mesh_N[i2*3+1], N2z = mesh_N[i2*3+2];

    // edge vectors (same formulas as before)
    const float E0x = V0x - V2x, E0y = V0y - V2y, E0z = V0z - V2z;
    const float E1x = V1x - V2x, E1y = V1y - V2y, E1z = V1z - V2z;
    const float F0x = N0x - N2x, F0y = N0y - N2y, F0z = N0z - N2z;
    const float F1x = N1x - N2x, F1y = N1y - N2y, F1z = N1z - N2z;

    // per-lane operand selects (loop-invariant parts)
    const float Aux = isV ? E1x : E0x;   // A when !isD (the isD case is nh, per-iter)
    const float Auy = isV ? E1y : E0y;
    const float Auz = isV ? E1z : E0z;
    const float Bx  = isD ? 0.0f : (isV ? F1x : F0x);
    const float By  = isD ? 0.0f : (isV ? F1y : F0y);
    const float Bz  = isD ? 0.0f : (isV ? F1z : F0z);

    const float tx = qx * SCALE, ty = qy * SCALE, tz = qz * SCALE;
    const float GS = 2.0f / (3.0f * 16384.0f);
    const float B1c = 0.9f,  ONE_M_B1 = 1.0f - 0.9f;
    const float B2c = 0.999f, ONE_M_B2 = 1.0f - 0.999f;

    float vwu = 1.0f / 3.0f, vwv = 1.0f / 3.0f;

#define SOLVE_STEP(RB1, RB2)                                                   \
    {                                                                          \
        const float du = qbcast<0>(dlt);                                       \
        const float dv = qbcast<1>(dlt);                                       \
        const float dd = qbcast<2>(dlt);                                       \
        const float bu = vwu + du;                                             \
        const float bv = vwv + dv;                                             \
        const float bw = (1.0f - bu) - bv;                                     \
        const float cVx = ((bu * V0x + bv * V1x) + bw * V2x) * SCALE;          \
        const float cVy = ((bu * V0y + bv * V1y) + bw * V2y) * SCALE;          \
        const float cVz = ((bu * V0z + bv * V1z) + bw * V2z) * SCALE;          \
        const float nrx = (bu * N0x + bv * N1x) + bw * N2x;                    \
        const float nry = (bu * N0y + bv * N1y) + bw * N2y;                    \
        const float nrz = (bu * N0z + bv * N1z) + bw * N2z;                    \
        const float nn  = (nrx * nrx + nry * nry) + nrz * nrz;                 \
        const float inv = __builtin_amdgcn_rsqf(nn);                           \
        const float nhx = nrx * inv, nhy = nry * inv, nhz = nrz * inv;         \
        const float cNx = nhx * SCALE, cNy = nhy * SCALE, cNz = nhz * SCALE;   \
        const float rx = (cVx + cNx * dd) - tx;                                \
        const float ry = (cVy + cNy * dd) - ty;                                \
        const float rz = (cVz + cNz * dd) - tz;                                \
        const float Ax = isD ? nhx : Aux;                                      \
        const float Ay = isD ? nhy : Auy;                                      \
        const float Az = isD ? nhz : Auz;                                      \
        const float dotA = (rx * Ax + ry * Ay) + rz * Az;                      \
        const float dotB = (rx * Bx + ry * By) + rz * Bz;                      \
        const float nhB  = (nhx * Bx + nhy * By) + nhz * Bz;                   \
        const float nr_r = qbcast<2>(dotA);                                    \
        const float g = GS * (SCALE * dotA + (dd * SCALE) * ((dotB - nr_r * nhB) * inv)); \
        mA = B1c * mA + ONE_M_B1 * g;                                          \
        vA = B2c * vA + ONE_M_B2 * (g * g);                                    \
        const float s = __builtin_amdgcn_rsqf(vA * (RB2) + 1e-16f);            \
        dlt -= 0.01f * (mA * (RB1)) * s;                                       \
    }

    for (int outer = 0; outer < kOuter; ++outer) {
        const float bw0 = (1.0f - vwu) - vwv;
        const float px = ((vwu * V0x + vwv * V1x) + bw0 * V2x);
        const float py = ((vwu * V0y + vwv * V1y) + bw0 * V2y);
        const float pz = ((vwu * V0z + vwv * V1z) + bw0 * V2z);
        const float dx = px - qx, dy = py - qy, dz = pz - qz;
        const float d0 = __builtin_amdgcn_sqrtf((dx * dx + dy * dy) + dz * dz);

        float dlt = isD ? d0 : 0.0f;   // this lane's channel delta
        float mA  = 0.0f, vA = 0.0f;

        float rbA1 = kTabP.rb[0][0], rbA2 = kTabP.rb[0][1];
        float rbB1 = kTabP.rb[1][0], rbB2 = kTabP.rb[1][1];
#pragma unroll 1
        for (int it2 = 0; it2 < kInner / 2; ++it2) {
            const float n1a = kTabP.rb[2 * it2 + 2][0];
            const float n2a = kTabP.rb[2 * it2 + 2][1];
            const float n1b = kTabP.rb[2 * it2 + 3][0];
            const float n2b = kTabP.rb[2 * it2 + 3][1];
            SOLVE_STEP(rbA1, rbA2);
            SOLVE_STEP(rbB1, rbB2);
            rbA1 = n1a; rbA2 = n2a; rbB1 = n1b; rbB2 = n2b;
        }
        vwu += qbcast<0>(dlt);
        vwv += qbcast<1>(dlt);
    }
#undef SOLVE_STEP

    if (ch == 0) {
        out[kPts + 2 * p + 0] = vwu;
        out[kPts + 2 * p + 1] = vwv;
        out[3 * kPts + p]     = 0.0f;   // outlier_mask = False
    }
}

extern "C" void kernel_launch(void* const* d_in, const int* in_sizes, int n_in,
                              void* d_out, int out_size, void* d_ws, size_t ws_size,
                              hipStream_t stream) {
    const float* verts  = (const float*)d_in[0];
    const float* mesh_V = (const float*)d_in[1];
    const float* mesh_N = (const float*)d_in[2];
    const int*   mesh_F = (const int*)d_in[3];
    float* out = (float*)d_out;

    // workspace layout: d2 candidates [8][kPts] | face candidates [8][kPts]
    float* ws_d2 = (float*)d_ws;
    int*   ws_f  = (int*)((char*)ws_d2 + KNN_SEG * kPts * sizeof(float));

    hipLaunchKernelGGL(knn_kernel,   dim3(kPtGroups * KNN_SEG), dim3(1024), 0, stream,
                       verts, mesh_V, mesh_F, ws_d2, ws_f);
    hipLaunchKernelGGL(solve_kernel, dim3(kPts * 4 / 256), dim3(256), 0, stream,
                       verts, mesh_V, mesh_N, mesh_F, ws_d2, ws_f, out);
}

// Round 13
// 113.338 us; speedup vs baseline: 1.1070x; 1.0561x over previous
//
#include <hip/hip_runtime.h>
#include <math.h>
#include <stdint.h>

// Problem constants (match reference)
constexpr int kVerts = 5000;
constexpr int kFaces = 10000;
constexpr int kPts   = 16384;   // BATCH * N_PTS = 2 * 8192
constexpr int kOuter = 4;
constexpr int kInner = 50;

#define SCALE 10.0f

// KNN structure (frozen from round 12): 4 pts/lane, 16 waves/block, 8 face
// segments, 512 blocks, LDS 52.8KB (2 blocks/CU). Rounds 11/12 established
// knn is invariant to staging style, pipelining, and occupancy at ~37us;
// eval core is at its 6-inst floor.
#define KNN_WAVES 16
#define KNN_SEG   8
constexpr int kSeg         = kFaces / KNN_SEG;       // 1250
constexpr int kPairsE      = kSeg / 2;               // 625
constexpr int kPtsPerLane  = 4;
constexpr int kPtsPerBlock = 64 * kPtsPerLane;       // 256
constexpr int kPtGroups    = kPts / kPtsPerBlock;    // 64

// ---------------------------------------------------------------------------
// Adam bias-correction table (same constexpr values as all prior rounds).
// ---------------------------------------------------------------------------
struct BiasTabP { float rb[kInner + 2][2]; };
constexpr BiasTabP make_tabp() {
    BiasTabP t{};
    float b1 = 1.0f, b2 = 1.0f;
    for (int i = 0; i < kInner; ++i) {
        b1 *= 0.9f; b2 *= 0.999f;
        t.rb[i][0] = 1.0f / (1.0f - b1);
        t.rb[i][1] = 1.0f / (1.0f - b2);
    }
    t.rb[kInner][0]     = t.rb[kInner - 1][0];
    t.rb[kInner][1]     = t.rb[kInner - 1][1];
    t.rb[kInner + 1][0] = t.rb[kInner - 1][0];
    t.rb[kInner + 1][1] = t.rb[kInner - 1][1];
    return t;
}
constexpr BiasTabP kTabP = make_tabp();

// ---------------------------------------------------------------------------
// Kernel 1: KNN (K=1), centers fused — FROZEN (round-12 version).
// ---------------------------------------------------------------------------
__global__ __launch_bounds__(1024, 8)
void knn_kernel(const float* __restrict__ verts,
                const float* __restrict__ mesh_V,
                const int*   __restrict__ mesh_F,
                float*       __restrict__ ws_d2,    // [KNN_SEG][kPts]
                int*         __restrict__ ws_f)     // [KNN_SEG][kPts]
{
    __shared__ float4 s_A[kPairsE];                        // {cx_e,cx_o,cy_e,cy_o}
    __shared__ float4 s_B[kPairsE];                        // {cz_e,cz_o,cc_e,cc_o}
    __shared__ float  s_best [KNN_WAVES][kPtsPerBlock];    // 16384 B
    __shared__ int    s_bestf[KNN_WAVES][kPtsPerBlock];    // 16384 B

    const int tid  = threadIdx.x;
    const int lane = tid & 63;
    const int wv   = __builtin_amdgcn_readfirstlane(tid >> 6);   // 0..15
    const int pg   = blockIdx.x >> 3;   // point group 0..63
    const int fq   = blockIdx.x & 7;    // face segment 0..7
    const int qbeg = fq * kSeg;

    // ---- fused centers: one face-pair per thread, b128 writes ----
    // (bit-identical *_rn formulas as every prior round)
    for (int j = tid; j < kPairsE; j += 1024) {
        const int f0 = qbeg + 2 * j;
        const int f1 = f0 + 1;
        const int a0 = mesh_F[f0 * 3 + 0], a1 = mesh_F[f0 * 3 + 1], a2 = mesh_F[f0 * 3 + 2];
        const int b0 = mesh_F[f1 * 3 + 0], b1 = mesh_F[f1 * 3 + 1], b2 = mesh_F[f1 * 3 + 2];
        const float cx0 = __fdiv_rn(__fadd_rn(__fadd_rn(mesh_V[a0*3+0], mesh_V[a1*3+0]), mesh_V[a2*3+0]), 3.0f);
        const float cy0 = __fdiv_rn(__fadd_rn(__fadd_rn(mesh_V[a0*3+1], mesh_V[a1*3+1]), mesh_V[a2*3+1]), 3.0f);
        const float cz0 = __fdiv_rn(__fadd_rn(__fadd_rn(mesh_V[a0*3+2], mesh_V[a1*3+2]), mesh_V[a2*3+2]), 3.0f);
        const float cc0 = __fadd_rn(__fadd_rn(__fmul_rn(cx0, cx0), __fmul_rn(cy0, cy0)),
                                    __fmul_rn(cz0, cz0));
        const float cx1 = __fdiv_rn(__fadd_rn(__fadd_rn(mesh_V[b0*3+0], mesh_V[b1*3+0]), mesh_V[b2*3+0]), 3.0f);
        const float cy1 = __fdiv_rn(__fadd_rn(__fadd_rn(mesh_V[b0*3+1], mesh_V[b1*3+1]), mesh_V[b2*3+1]), 3.0f);
        const float cz1 = __fdiv_rn(__fadd_rn(__fadd_rn(mesh_V[b0*3+2], mesh_V[b1*3+2]), mesh_V[b2*3+2]), 3.0f);
        const float cc1 = __fadd_rn(__fadd_rn(__fmul_rn(cx1, cx1), __fmul_rn(cy1, cy1)),
                                    __fmul_rn(cz1, cz1));
        s_A[j] = make_float4(cx0, cx1, cy0, cy1);
        s_B[j] = make_float4(cz0, cz1, cc0, cc1);
    }

    // ---- per-lane 4 points: pre-negated doubled coords (exact), scalar,
    //      laundered once (loop-invariant, no remat) ----
    float ndx[kPtsPerLane], ndy[kPtsPerLane], ndz[kPtsPerLane];
#pragma unroll
    for (int k = 0; k < kPtsPerLane; ++k) {
        const int p = pg * kPtsPerBlock + k * 64 + lane;
        const float qx = verts[p * 3 + 0];
        const float qy = verts[p * 3 + 1];
        const float qz = verts[p * 3 + 2];
        ndx[k] = -__fmul_rn(2.0f, qx);  asm("" : "+v"(ndx[k]));
        ndy[k] = -__fmul_rn(2.0f, qy);  asm("" : "+v"(ndy[k]));
        ndz[k] = -__fmul_rn(2.0f, qz);  asm("" : "+v"(ndz[k]));
    }

    float bd0[kPtsPerLane], bd1[kPtsPerLane];
    int   bf0[kPtsPerLane], bf1[kPtsPerLane];
#pragma unroll
    for (int k = 0; k < kPtsPerLane; ++k) {
        bd0[k] = INFINITY;   bd1[k] = INFINITY;
        bf0[k] = 0x7fffffff; bf1[k] = 0x7fffffff;
    }

    __syncthreads();

    // this wave's contiguous pair slice (~39 pairs)
    const int pbeg = (wv * kPairsE) / KNN_WAVES;
    const int pend = ((wv + 1) * kPairsE) / KNN_WAVES;

#pragma unroll 2
    for (int fp = pbeg; fp < pend; ++fp) {
        // 2 x ds_read_b128 at wave-uniform address (broadcast, in-order)
        const float4 ab = s_A[fp];   // {cx_e, cx_o, cy_e, cy_o}
        const float4 zb = s_B[fp];   // {cz_e, cz_o, cc_e, cc_o}
        const int gf  = qbeg + 2 * fp;
        const int gf1 = gf + 1;
#pragma unroll
        for (int k = 0; k < kPtsPerLane; ++k) {
            // s = cc + (-2q).c as a pure FMA chain: 3 v_fma_f32 per eval
            const float s0 = __builtin_fmaf(ndx[k], ab.x,
                             __builtin_fmaf(ndy[k], ab.z,
                             __builtin_fmaf(ndz[k], zb.x, zb.z)));
            const float s1 = __builtin_fmaf(ndx[k], ab.y,
                             __builtin_fmaf(ndy[k], ab.w,
                             __builtin_fmaf(ndz[k], zb.y, zb.w)));
            // branch-free: v_cmp + v_cndmask (index) + v_min_f32 (dist);
            // strict < keeps the OLD (smaller) face on exact ties.
            bf0[k] = (s0 < bd0[k]) ? gf  : bf0[k];
            bd0[k] = __builtin_fminf(s0, bd0[k]);
            bf1[k] = (s1 < bd1[k]) ? gf1 : bf1[k];
            bd1[k] = __builtin_fminf(s1, bd1[k]);
        }
    }

    // per-point lexicographic merge of the 2 accumulators (smaller f on ties)
#pragma unroll
    for (int k = 0; k < kPtsPerLane; ++k) {
        if (bd1[k] < bd0[k] || (bd1[k] == bd0[k] && bf1[k] < bf0[k])) {
            bd0[k] = bd1[k]; bf0[k] = bf1[k];
        }
        s_best [wv][k * 64 + lane] = bd0[k];
        s_bestf[wv][k * 64 + lane] = bf0[k];
    }
    __syncthreads();

    // cross-wave merge: fully lexicographic -> partition-independent
    if (tid < kPtsPerBlock) {
        float best  = s_best [0][tid];
        int   bestf = s_bestf[0][tid];
#pragma unroll
        for (int w = 1; w < KNN_WAVES; ++w) {
            const float ob = s_best [w][tid];
            const int   of = s_bestf[w][tid];
            if (ob < best || (ob == best && of < bestf)) { best = ob; bestf = of; }
        }
        const int p = pg * kPtsPerBlock + tid;
        ws_d2[fq * kPts + p] = best;
        ws_f [fq * kPts + p] = bestf;
    }
}

// ---------------------------------------------------------------------------
// quad_perm DPP broadcast: all lanes of each 4-lane quad read lane K.
// ---------------------------------------------------------------------------
template<int K>
__device__ __forceinline__ float qbcast(float v) {
    return __int_as_float(__builtin_amdgcn_update_dpp(
        0, __float_as_int(v), K * 0x55 /*quad_perm[K,K,K,K]*/, 0xF, 0xF, true));
}

// ---------------------------------------------------------------------------
// Kernel 2: solve — round-13 change: EDGE-FORM interpolation.
//   interp(X) = X2 + bu*(X0-X2) + bv*(X1-X2)   (algebraically == bary form)
// with SCALE and the target fold into precomputed per-lane constants:
//   cV - t = fma(bu,SE0, fma(bv,SE1, SV2t)),  SV2t = SCALE*V2 - t
//   nr     = fma(bu,F0,  fma(bv,F1,  N2))
//   r      = fma(nh, ddS, cVmt),              ddS  = dd*SCALE (shared w/ g)
// Cuts ~17 VALU/iter (-20%) and ~4 dependency levels from the 200-step
// serial Adam loop (solve is latency-bound at 1 wave/SIMD; r8 proved
// issue is not the limit). NOT bit-exact with prior rounds (new rounding
// regime for vw); fidx untouched (knn + merges frozen). Prior regimes
// 0.3276/0.3281/0.3335 all passed -> bounded risk, revert if absmax jumps.
// ---------------------------------------------------------------------------
__global__ __launch_bounds__(256)
void solve_kernel(const float* __restrict__ verts,
                  const float* __restrict__ mesh_V,
                  const float* __restrict__ mesh_N,
                  const int*   __restrict__ mesh_F,
                  const float* __restrict__ ws_d2,
                  const int*   __restrict__ ws_f,
                  float*       __restrict__ out)
{
    const int t  = blockIdx.x * 256 + threadIdx.x;
    const int p  = t >> 2;          // point index
    const int ch = t & 3;           // 0=u, 1=v, 2=d, 3=d-duplicate
    const bool isV = (ch == 1);
    const bool isD = (ch >= 2);

    // merge segments: ascending order + strict < == first-occurrence argmin
    float bdm = ws_d2[p];
    int   f   = ws_f[p];
#pragma unroll
    for (int q = 1; q < KNN_SEG; ++q) {
        const float d  = ws_d2[q * kPts + p];
        const int   ff = ws_f [q * kPts + p];
        if (d < bdm) { bdm = d; f = ff; }
    }
    if (ch == 0) out[p] = (float)f;   // fidx as float (exact for idx < 2^24)

    const float qx = verts[p * 3 + 0];
    const float qy = verts[p * 3 + 1];
    const float qz = verts[p * 3 + 2];

    const int i0 = mesh_F[f * 3 + 0];
    const int i1 = mesh_F[f * 3 + 1];
    const int i2 = mesh_F[f * 3 + 2];

    const float V0x = mesh_V[i0*3+0], V0y = mesh_V[i0*3+1], V0z = mesh_V[i0*3+2];
    const float V1x = mesh_V[i1*3+0], V1y = mesh_V[i1*3+1], V1z = mesh_V[i1*3+2];
    const float V2x = mesh_V[i2*3+0], V2y = mesh_V[i2*3+1], V2z = mesh_V[i2*3+2];
    const float N0x = mesh_N[i0*3+0], N0y = mesh_N[i0*3+1], N0z = mesh_N[i0*3+2];
    const float N1x = mesh_N[i1*3+0], N1y = mesh_N[i1*3+1], N1z = mesh_N[i1*3+2];
    const float N2x = mesh_N[i2*3+0], N2y = mesh_N[i2*3+1], N2z = mesh_N[i2*3+2];

    // edge vectors (also the gradient dot operands, unscaled)
    const float E0x = V0x - V2x, E0y = V0y - V2y, E0z = V0z - V2z;
    const float E1x = V1x - V2x, E1y = V1y - V2y, E1z = V1z - V2z;
    const float F0x = N0x - N2x, F0y = N0y - N2y, F0z = N0z - N2z;
    const float F1x = N1x - N2x, F1y = N1y - N2y, F1z = N1z - N2z;

    const float tx = qx * SCALE, ty = qy * SCALE, tz = qz * SCALE;

    // scaled interpolation constants (setup-only cost)
    const float SE0x = SCALE * E0x, SE0y = SCALE * E0y, SE0z = SCALE * E0z;
    const float SE1x = SCALE * E1x, SE1y = SCALE * E1y, SE1z = SCALE * E1z;
    const float SV2tx = SCALE * V2x - tx;
    const float SV2ty = SCALE * V2y - ty;
    const float SV2tz = SCALE * V2z - tz;

    // per-lane operand selects (loop-invariant parts)
    const float Aux = isV ? E1x : E0x;   // A when !isD (the isD case is nh, per-iter)
    const float Auy = isV ? E1y : E0y;
    const float Auz = isV ? E1z : E0z;
    const float Bx  = isD ? 0.0f : (isV ? F1x : F0x);
    const float By  = isD ? 0.0f : (isV ? F1y : F0y);
    const float Bz  = isD ? 0.0f : (isV ? F1z : F0z);

    const float GS = 2.0f / (3.0f * 16384.0f);
    const float B1c = 0.9f,  ONE_M_B1 = 1.0f - 0.9f;
    const float B2c = 0.999f, ONE_M_B2 = 1.0f - 0.999f;

    float vwu = 1.0f / 3.0f, vwv = 1.0f / 3.0f;

#define SOLVE_STEP(RB1, RB2)                                                   \
    {                                                                          \
        const float du = qbcast<0>(dlt);                                       \
        const float dv = qbcast<1>(dlt);                                       \
        const float dd = qbcast<2>(dlt);                                       \
        const float bu = vwu + du;                                             \
        const float bv = vwv + dv;                                             \
        const float ddS = dd * SCALE;                                          \
        const float nrx = __builtin_fmaf(bu, F0x, __builtin_fmaf(bv, F1x, N2x)); \
        const float nry = __builtin_fmaf(bu, F0y, __builtin_fmaf(bv, F1y, N2y)); \
        const float nrz = __builtin_fmaf(bu, F0z, __builtin_fmaf(bv, F1z, N2z)); \
        const float nn  = (nrx * nrx + nry * nry) + nrz * nrz;                 \
        const float inv = __builtin_amdgcn_rsqf(nn);                           \
        const float nhx = nrx * inv, nhy = nry * inv, nhz = nrz * inv;         \
        const float cVmtx = __builtin_fmaf(bu, SE0x, __builtin_fmaf(bv, SE1x, SV2tx)); \
        const float cVmty = __builtin_fmaf(bu, SE0y, __builtin_fmaf(bv, SE1y, SV2ty)); \
        const float cVmtz = __builtin_fmaf(bu, SE0z, __builtin_fmaf(bv, SE1z, SV2tz)); \
        const float rx = __builtin_fmaf(nhx, ddS, cVmtx);                      \
        const float ry = __builtin_fmaf(nhy, ddS, cVmty);                      \
        const float rz = __builtin_fmaf(nhz, ddS, cVmtz);                      \
        const float Ax = isD ? nhx : Aux;                                      \
        const float Ay = isD ? nhy : Auy;                                      \
        const float Az = isD ? nhz : Auz;                                      \
        const float dotA = (rx * Ax + ry * Ay) + rz * Az;                      \
        const float dotB = (rx * Bx + ry * By) + rz * Bz;                      \
        const float nhB  = (nhx * Bx + nhy * By) + nhz * Bz;                   \
        const float nr_r = qbcast<2>(dotA);                                    \
        const float g = GS * (SCALE * dotA + ddS * ((dotB - nr_r * nhB) * inv)); \
        mA = B1c * mA + ONE_M_B1 * g;                                          \
        vA = B2c * vA + ONE_M_B2 * (g * g);                                    \
        const float s = __builtin_amdgcn_rsqf(vA * (RB2) + 1e-16f);            \
        dlt -= 0.01f * (mA * (RB1)) * s;                                       \
    }

    for (int outer = 0; outer < kOuter; ++outer) {
        const float bw0 = (1.0f - vwu) - vwv;
        const float px = ((vwu * V0x + vwv * V1x) + bw0 * V2x);
        const float py = ((vwu * V0y + vwv * V1y) + bw0 * V2y);
        const float pz = ((vwu * V0z + vwv * V1z) + bw0 * V2z);
        const float dx = px - qx, dy = py - qy, dz = pz - qz;
        const float d0 = __builtin_amdgcn_sqrtf((dx * dx + dy * dy) + dz * dz);

        float dlt = isD ? d0 : 0.0f;   // this lane's channel delta
        float mA  = 0.0f, vA = 0.0f;

        float rbA1 = kTabP.rb[0][0], rbA2 = kTabP.rb[0][1];
        float rbB1 = kTabP.rb[1][0], rbB2 = kTabP.rb[1][1];
#pragma unroll 1
        for (int it2 = 0; it2 < kInner / 2; ++it2) {
            const float n1a = kTabP.rb[2 * it2 + 2][0];
            const float n2a = kTabP.rb[2 * it2 + 2][1];
            const float n1b = kTabP.rb[2 * it2 + 3][0];
            const float n2b = kTabP.rb[2 * it2 + 3][1];
            SOLVE_STEP(rbA1, rbA2);
            SOLVE_STEP(rbB1, rbB2);
            rbA1 = n1a; rbA2 = n2a; rbB1 = n1b; rbB2 = n2b;
        }
        vwu += qbcast<0>(dlt);
        vwv += qbcast<1>(dlt);
    }
#undef SOLVE_STEP

    if (ch == 0) {
        out[kPts + 2 * p + 0] = vwu;
        out[kPts + 2 * p + 1] = vwv;
        out[3 * kPts + p]     = 0.0f;   // outlier_mask = False
    }
}

extern "C" void kernel_launch(void* const* d_in, const int* in_sizes, int n_in,
                              void* d_out, int out_size, void* d_ws, size_t ws_size,
                              hipStream_t stream) {
    const float* verts  = (const float*)d_in[0];
    const float* mesh_V = (const float*)d_in[1];
    const float* mesh_N = (const float*)d_in[2];
    const int*   mesh_F = (const int*)d_in[3];
    float* out = (float*)d_out;

    // workspace layout: d2 candidates [8][kPts] | face candidates [8][kPts]
    float* ws_d2 = (float*)d_ws;
    int*   ws_f  = (int*)((char*)ws_d2 + KNN_SEG * kPts * sizeof(float));

    hipLaunchKernelGGL(knn_kernel,   dim3(kPtGroups * KNN_SEG), dim3(1024), 0, stream,
                       verts, mesh_V, mesh_F, ws_d2, ws_f);
    hipLaunchKernelGGL(solve_kernel, dim3(kPts * 4 / 256), dim3(256), 0, stream,
                       verts, mesh_V, mesh_N, mesh_F, ws_d2, ws_f, out);
}

// Round 15
// 112.634 us; speedup vs baseline: 1.1139x; 1.0063x over previous
//
#include <hip/hip_runtime.h>
#include <math.h>
#include <stdint.h>

// Problem constants (match reference)
constexpr int kVerts = 5000;
constexpr int kFaces = 10000;
constexpr int kPts   = 16384;   // BATCH * N_PTS = 2 * 8192
constexpr int kOuter = 4;
constexpr int kInner = 50;

#define SCALE 10.0f

// KNN structure (FROZEN since round 12): 4 pts/lane, 16 waves/block, 8 face
// segments, 512 blocks, LDS 52.8KB (2 blocks/CU). Established invariants:
// knn ~37us regardless of staging style (r11), pipelining (r11), occupancy
// 16->32 waves/CU (r12), eval 10->6 insts (r10, -6.4us total). Measured
// issue floor ~27us (r9 counters: 2.2x inst overhead over the 6/eval core).
#define KNN_WAVES 16
#define KNN_SEG   8
constexpr int kSeg         = kFaces / KNN_SEG;       // 1250
constexpr int kPairsE      = kSeg / 2;               // 625
constexpr int kPtsPerLane  = 4;
constexpr int kPtsPerBlock = 64 * kPtsPerLane;       // 256
constexpr int kPtGroups    = kPts / kPtsPerBlock;    // 64

// ---------------------------------------------------------------------------
// Adam bias-correction table. Round-14: [0] now stores LR1 = 0.01/(1-b1^t)
// (0.01 folded in at compile time; one fewer runtime mul per step).
// ---------------------------------------------------------------------------
struct BiasTabP { float rb[kInner + 2][2]; };
constexpr BiasTabP make_tabp() {
    BiasTabP t{};
    float b1 = 1.0f, b2 = 1.0f;
    for (int i = 0; i < kInner; ++i) {
        b1 *= 0.9f; b2 *= 0.999f;
        t.rb[i][0] = 0.01f / (1.0f - b1);   // LR1
        t.rb[i][1] = 1.0f / (1.0f - b2);    // RB2
    }
    t.rb[kInner][0]     = t.rb[kInner - 1][0];
    t.rb[kInner][1]     = t.rb[kInner - 1][1];
    t.rb[kInner + 1][0] = t.rb[kInner - 1][0];
    t.rb[kInner + 1][1] = t.rb[kInner - 1][1];
    return t;
}
constexpr BiasTabP kTabP = make_tabp();

// ---------------------------------------------------------------------------
// Kernel 1: KNN (K=1), centers fused — FROZEN (round-12/13 version).
// ---------------------------------------------------------------------------
__global__ __launch_bounds__(1024, 8)
void knn_kernel(const float* __restrict__ verts,
                const float* __restrict__ mesh_V,
                const int*   __restrict__ mesh_F,
                float*       __restrict__ ws_d2,    // [KNN_SEG][kPts]
                int*         __restrict__ ws_f)     // [KNN_SEG][kPts]
{
    __shared__ float4 s_A[kPairsE];                        // {cx_e,cx_o,cy_e,cy_o}
    __shared__ float4 s_B[kPairsE];                        // {cz_e,cz_o,cc_e,cc_o}
    __shared__ float  s_best [KNN_WAVES][kPtsPerBlock];    // 16384 B
    __shared__ int    s_bestf[KNN_WAVES][kPtsPerBlock];    // 16384 B

    const int tid  = threadIdx.x;
    const int lane = tid & 63;
    const int wv   = __builtin_amdgcn_readfirstlane(tid >> 6);   // 0..15
    const int pg   = blockIdx.x >> 3;   // point group 0..63
    const int fq   = blockIdx.x & 7;    // face segment 0..7
    const int qbeg = fq * kSeg;

    // ---- fused centers: one face-pair per thread, b128 writes ----
    // (bit-identical *_rn formulas as every prior round)
    for (int j = tid; j < kPairsE; j += 1024) {
        const int f0 = qbeg + 2 * j;
        const int f1 = f0 + 1;
        const int a0 = mesh_F[f0 * 3 + 0], a1 = mesh_F[f0 * 3 + 1], a2 = mesh_F[f0 * 3 + 2];
        const int b0 = mesh_F[f1 * 3 + 0], b1 = mesh_F[f1 * 3 + 1], b2 = mesh_F[f1 * 3 + 2];
        const float cx0 = __fdiv_rn(__fadd_rn(__fadd_rn(mesh_V[a0*3+0], mesh_V[a1*3+0]), mesh_V[a2*3+0]), 3.0f);
        const float cy0 = __fdiv_rn(__fadd_rn(__fadd_rn(mesh_V[a0*3+1], mesh_V[a1*3+1]), mesh_V[a2*3+1]), 3.0f);
        const float cz0 = __fdiv_rn(__fadd_rn(__fadd_rn(mesh_V[a0*3+2], mesh_V[a1*3+2]), mesh_V[a2*3+2]), 3.0f);
        const float cc0 = __fadd_rn(__fadd_rn(__fmul_rn(cx0, cx0), __fmul_rn(cy0, cy0)),
                                    __fmul_rn(cz0, cz0));
        const float cx1 = __fdiv_rn(__fadd_rn(__fadd_rn(mesh_V[b0*3+0], mesh_V[b1*3+0]), mesh_V[b2*3+0]), 3.0f);
        const float cy1 = __fdiv_rn(__fadd_rn(__fadd_rn(mesh_V[b0*3+1], mesh_V[b1*3+1]), mesh_V[b2*3+1]), 3.0f);
        const float cz1 = __fdiv_rn(__fadd_rn(__fadd_rn(mesh_V[b0*3+2], mesh_V[b1*3+2]), mesh_V[b2*3+2]), 3.0f);
        const float cc1 = __fadd_rn(__fadd_rn(__fmul_rn(cx1, cx1), __fmul_rn(cy1, cy1)),
                                    __fmul_rn(cz1, cz1));
        s_A[j] = make_float4(cx0, cx1, cy0, cy1);
        s_B[j] = make_float4(cz0, cz1, cc0, cc1);
    }

    // ---- per-lane 4 points: pre-negated doubled coords (exact), scalar,
    //      laundered once (loop-invariant, no remat) ----
    float ndx[kPtsPerLane], ndy[kPtsPerLane], ndz[kPtsPerLane];
#pragma unroll
    for (int k = 0; k < kPtsPerLane; ++k) {
        const int p = pg * kPtsPerBlock + k * 64 + lane;
        const float qx = verts[p * 3 + 0];
        const float qy = verts[p * 3 + 1];
        const float qz = verts[p * 3 + 2];
        ndx[k] = -__fmul_rn(2.0f, qx);  asm("" : "+v"(ndx[k]));
        ndy[k] = -__fmul_rn(2.0f, qy);  asm("" : "+v"(ndy[k]));
        ndz[k] = -__fmul_rn(2.0f, qz);  asm("" : "+v"(ndz[k]));
    }

    float bd0[kPtsPerLane], bd1[kPtsPerLane];
    int   bf0[kPtsPerLane], bf1[kPtsPerLane];
#pragma unroll
    for (int k = 0; k < kPtsPerLane; ++k) {
        bd0[k] = INFINITY;   bd1[k] = INFINITY;
        bf0[k] = 0x7fffffff; bf1[k] = 0x7fffffff;
    }

    __syncthreads();

    // this wave's contiguous pair slice (~39 pairs)
    const int pbeg = (wv * kPairsE) / KNN_WAVES;
    const int pend = ((wv + 1) * kPairsE) / KNN_WAVES;

#pragma unroll 2
    for (int fp = pbeg; fp < pend; ++fp) {
        // 2 x ds_read_b128 at wave-uniform address (broadcast, in-order)
        const float4 ab = s_A[fp];   // {cx_e, cx_o, cy_e, cy_o}
        const float4 zb = s_B[fp];   // {cz_e, cz_o, cc_e, cc_o}
        const int gf  = qbeg + 2 * fp;
        const int gf1 = gf + 1;
#pragma unroll
        for (int k = 0; k < kPtsPerLane; ++k) {
            // s = cc + (-2q).c as a pure FMA chain: 3 v_fma_f32 per eval
            const float s0 = __builtin_fmaf(ndx[k], ab.x,
                             __builtin_fmaf(ndy[k], ab.z,
                             __builtin_fmaf(ndz[k], zb.x, zb.z)));
            const float s1 = __builtin_fmaf(ndx[k], ab.y,
                             __builtin_fmaf(ndy[k], ab.w,
                             __builtin_fmaf(ndz[k], zb.y, zb.w)));
            // branch-free: v_cmp + v_cndmask (index) + v_min_f32 (dist);
            // strict < keeps the OLD (smaller) face on exact ties.
            bf0[k] = (s0 < bd0[k]) ? gf  : bf0[k];
            bd0[k] = __builtin_fminf(s0, bd0[k]);
            bf1[k] = (s1 < bd1[k]) ? gf1 : bf1[k];
            bd1[k] = __builtin_fminf(s1, bd1[k]);
        }
    }

    // per-point lexicographic merge of the 2 accumulators (smaller f on ties)
#pragma unroll
    for (int k = 0; k < kPtsPerLane; ++k) {
        if (bd1[k] < bd0[k] || (bd1[k] == bd0[k] && bf1[k] < bf0[k])) {
            bd0[k] = bd1[k]; bf0[k] = bf1[k];
        }
        s_best [wv][k * 64 + lane] = bd0[k];
        s_bestf[wv][k * 64 + lane] = bf0[k];
    }
    __syncthreads();

    // cross-wave merge: fully lexicographic -> partition-independent
    if (tid < kPtsPerBlock) {
        float best  = s_best [0][tid];
        int   bestf = s_bestf[0][tid];
#pragma unroll
        for (int w = 1; w < KNN_WAVES; ++w) {
            const float ob = s_best [w][tid];
            const int   of = s_bestf[w][tid];
            if (ob < best || (ob == best && of < bestf)) { best = ob; bestf = of; }
        }
        const int p = pg * kPtsPerBlock + tid;
        ws_d2[fq * kPts + p] = best;
        ws_f [fq * kPts + p] = bestf;
    }
}

// ---------------------------------------------------------------------------
// quad_perm DPP broadcast: all lanes of each 4-lane quad read lane K.
// ---------------------------------------------------------------------------
template<int K>
__device__ __forceinline__ float qbcast(float v) {
    return __int_as_float(__builtin_amdgcn_update_dpp(
        0, __float_as_int(v), K * 0x55 /*quad_perm[K,K,K,K]*/, 0xF, 0xF, true));
}

// ---------------------------------------------------------------------------
// Kernel 2: solve — round-14 critical-path trims (solve is chain-bound at
// 1 wave/SIMD; ~372 cyc/iter measured vs ~110 cyc issue):
//  (1) broadcast the Adam STEP, not dlt: bu/bv/ddS are per-lane running
//      state (bu -= qb(step); ddS = fma(-SCALE, qb(step), ddS)); the dlt
//      accumulation moves off the critical path. -1 level.
//  (2) g = fma(GSdd, w, GSS*dotA): GSS=GS*SCALE folded, GSS*dotA computed
//      in parallel with the nr_r DPP broadcast; GSdd = GS*ddS at iter
//      start. -2 levels after nr_r.
//  (3) LR1 = 0.01/(1-b1^t) folded into the table. -1 mul.
// New rounding regime for vw (5th; 0.3276/0.3281/0.3335/0.3325 all passed);
// fidx untouched (knn + merges frozen).
// ---------------------------------------------------------------------------
__global__ __launch_bounds__(256)
void solve_kernel(const float* __restrict__ verts,
                  const float* __restrict__ mesh_V,
                  const float* __restrict__ mesh_N,
                  const int*   __restrict__ mesh_F,
                  const float* __restrict__ ws_d2,
                  const int*   __restrict__ ws_f,
                  float*       __restrict__ out)
{
    const int t  = blockIdx.x * 256 + threadIdx.x;
    const int p  = t >> 2;          // point index
    const int ch = t & 3;           // 0=u, 1=v, 2=d, 3=d-duplicate
    const bool isV = (ch == 1);
    const bool isD = (ch >= 2);

    // merge segments: ascending order + strict < == first-occurrence argmin
    float bdm = ws_d2[p];
    int   f   = ws_f[p];
#pragma unroll
    for (int q = 1; q < KNN_SEG; ++q) {
        const float d  = ws_d2[q * kPts + p];
        const int   ff = ws_f [q * kPts + p];
        if (d < bdm) { bdm = d; f = ff; }
    }
    if (ch == 0) out[p] = (float)f;   // fidx as float (exact for idx < 2^24)

    const float qx = verts[p * 3 + 0];
    const float qy = verts[p * 3 + 1];
    const float qz = verts[p * 3 + 2];

    const int i0 = mesh_F[f * 3 + 0];
    const int i1 = mesh_F[f * 3 + 1];
    const int i2 = mesh_F[f * 3 + 2];

    const float V0x = mesh_V[i0*3+0], V0y = mesh_V[i0*3+1], V0z = mesh_V[i0*3+2];
    const float V1x = mesh_V[i1*3+0], V1y = mesh_V[i1*3+1], V1z = mesh_V[i1*3+2];
    const float V2x = mesh_V[i2*3+0], V2y = mesh_V[i2*3+1], V2z = mesh_V[i2*3+2];
    const float N0x = mesh_N[i0*3+0], N0y = mesh_N[i0*3+1], N0z = mesh_N[i0*3+2];
    const float N1x = mesh_N[i1*3+0], N1y = mesh_N[i1*3+1], N1z = mesh_N[i1*3+2];
    const float N2x = mesh_N[i2*3+0], N2y = mesh_N[i2*3+1], N2z = mesh_N[i2*3+2];

    // edge vectors (also the gradient dot operands, unscaled)
    const float E0x = V0x - V2x, E0y = V0y - V2y, E0z = V0z - V2z;
    const float E1x = V1x - V2x, E1y = V1y - V2y, E1z = V1z - V2z;
    const float F0x = N0x - N2x, F0y = N0y - N2y, F0z = N0z - N2z;
    const float F1x = N1x - N2x, F1y = N1y - N2y, F1z = N1z - N2z;

    const float tx = qx * SCALE, ty = qy * SCALE, tz = qz * SCALE;

    // scaled interpolation constants (setup-only cost)
    const float SE0x = SCALE * E0x, SE0y = SCALE * E0y, SE0z = SCALE * E0z;
    const float SE1x = SCALE * E1x, SE1y = SCALE * E1y, SE1z = SCALE * E1z;
    const float SV2tx = SCALE * V2x - tx;
    const float SV2ty = SCALE * V2y - ty;
    const float SV2tz = SCALE * V2z - tz;

    // per-lane operand selects (loop-invariant parts)
    const float Aux = isV ? E1x : E0x;   // A when !isD (the isD case is nh, per-iter)
    const float Auy = isV ? E1y : E0y;
    const float Auz = isV ? E1z : E0z;
    const float Bx  = isD ? 0.0f : (isV ? F1x : F0x);
    const float By  = isD ? 0.0f : (isV ? F1y : F0y);
    const float Bz  = isD ? 0.0f : (isV ? F1z : F0z);

    const float GS  = 2.0f / (3.0f * 16384.0f);
    const float GSS = GS * SCALE;
    const float B1c = 0.9f,  ONE_M_B1 = 1.0f - 0.9f;
    const float B2c = 0.999f, ONE_M_B2 = 1.0f - 0.999f;

    float vwu = 1.0f / 3.0f, vwv = 1.0f / 3.0f;

#define SOLVE_STEP(LR1, RB2)                                                   \
    {                                                                          \
        const float GSdd = GS * ddS;                                           \
        const float nrx = __builtin_fmaf(bu, F0x, __builtin_fmaf(bv, F1x, N2x)); \
        const float nry = __builtin_fmaf(bu, F0y, __builtin_fmaf(bv, F1y, N2y)); \
        const float nrz = __builtin_fmaf(bu, F0z, __builtin_fmaf(bv, F1z, N2z)); \
        const float nn  = (nrx * nrx + nry * nry) + nrz * nrz;                 \
        const float inv = __builtin_amdgcn_rsqf(nn);                           \
        const float nhx = nrx * inv, nhy = nry * inv, nhz = nrz * inv;         \
        const float cVmtx = __builtin_fmaf(bu, SE0x, __builtin_fmaf(bv, SE1x, SV2tx)); \
        const float cVmty = __builtin_fmaf(bu, SE0y, __builtin_fmaf(bv, SE1y, SV2ty)); \
        const float cVmtz = __builtin_fmaf(bu, SE0z, __builtin_fmaf(bv, SE1z, SV2tz)); \
        const float rx = __builtin_fmaf(nhx, ddS, cVmtx);                      \
        const float ry = __builtin_fmaf(nhy, ddS, cVmty);                      \
        const float rz = __builtin_fmaf(nhz, ddS, cVmtz);                      \
        const float Ax = isD ? nhx : Aux;                                      \
        const float Ay = isD ? nhy : Auy;                                      \
        const float Az = isD ? nhz : Auz;                                      \
        const float dotA = (rx * Ax + ry * Ay) + rz * Az;                      \
        const float dotB = (rx * Bx + ry * By) + rz * Bz;                      \
        const float nhB  = (nhx * Bx + nhy * By) + nhz * Bz;                   \
        const float preA = GSS * dotA;       /* parallel with the DPP */       \
        const float nr_r = qbcast<2>(dotA);                                    \
        const float w    = __builtin_fmaf(-nr_r, nhB, dotB) * inv;             \
        const float g    = __builtin_fmaf(GSdd, w, preA);                      \
        mA = B1c * mA + ONE_M_B1 * g;                                          \
        vA = B2c * vA + ONE_M_B2 * (g * g);                                    \
        const float s = __builtin_amdgcn_rsqf(__builtin_fmaf(vA, (RB2), 1e-16f)); \
        const float step = (mA * (LR1)) * s;                                   \
        dlt -= step;                          /* own lane, off critical path */\
        const float su = qbcast<0>(step);                                      \
        const float sv = qbcast<1>(step);                                      \
        const float sd = qbcast<2>(step);                                      \
        bu -= su;                                                              \
        bv -= sv;                                                              \
        ddS = __builtin_fmaf(-(SCALE), sd, ddS);                               \
    }

    for (int outer = 0; outer < kOuter; ++outer) {
        const float bw0 = (1.0f - vwu) - vwv;
        const float px = ((vwu * V0x + vwv * V1x) + bw0 * V2x);
        const float py = ((vwu * V0y + vwv * V1y) + bw0 * V2y);
        const float pz = ((vwu * V0z + vwv * V1z) + bw0 * V2z);
        const float dx = px - qx, dy = py - qy, dz = pz - qz;
        const float d0 = __builtin_amdgcn_sqrtf((dx * dx + dy * dy) + dz * dz);

        float dlt = isD ? d0 : 0.0f;   // this lane's channel delta (for vw update)
        float bu  = vwu, bv = vwv;     // running interpolation state
        float ddS = d0 * SCALE;        // running dd*SCALE
        float mA  = 0.0f, vA = 0.0f;

        float rbA1 = kTabP.rb[0][0], rbA2 = kTabP.rb[0][1];
        float rbB1 = kTabP.rb[1][0], rbB2 = kTabP.rb[1][1];
#pragma unroll 1
        for (int it2 = 0; it2 < kInner / 2; ++it2) {
            const float n1a = kTabP.rb[2 * it2 + 2][0];
            const float n2a = kTabP.rb[2 * it2 + 2][1];
            const float n1b = kTabP.rb[2 * it2 + 3][0];
            const float n2b = kTabP.rb[2 * it2 + 3][1];
            SOLVE_STEP(rbA1, rbA2);
            SOLVE_STEP(rbB1, rbB2);
            rbA1 = n1a; rbA2 = n2a; rbB1 = n1b; rbB2 = n2b;
        }
        vwu += qbcast<0>(dlt);
        vwv += qbcast<1>(dlt);
    }
#undef SOLVE_STEP

    if (ch == 0) {
        out[kPts + 2 * p + 0] = vwu;
        out[kPts + 2 * p + 1] = vwv;
        out[3 * kPts + p]     = 0.0f;   // outlier_mask = False
    }
}

extern "C" void kernel_launch(void* const* d_in, const int* in_sizes, int n_in,
                              void* d_out, int out_size, void* d_ws, size_t ws_size,
                              hipStream_t stream) {
    const float* verts  = (const float*)d_in[0];
    const float* mesh_V = (const float*)d_in[1];
    const float* mesh_N = (const float*)d_in[2];
    const int*   mesh_F = (const int*)d_in[3];
    float* out = (float*)d_out;

    // workspace layout: d2 candidates [8][kPts] | face candidates [8][kPts]
    float* ws_d2 = (float*)d_ws;
    int*   ws_f  = (int*)((char*)ws_d2 + KNN_SEG * kPts * sizeof(float));

    hipLaunchKernelGGL(knn_kernel,   dim3(kPtGroups * KNN_SEG), dim3(1024), 0, stream,
                       verts, mesh_V, mesh_F, ws_d2, ws_f);
    hipLaunchKernelGGL(solve_kernel, dim3(kPts * 4 / 256), dim3(256), 0, stream,
                       verts, mesh_V, mesh_N, mesh_F, ws_d2, ws_f, out);
}